// Round 5
// baseline (2163.189 us; speedup 1.0000x reference)
//
#include <hip/hip_runtime.h>

// GraphTransformerLayer fused pipeline for MI355X (gfx950).
// T=64, B=32, E=512, F=2048, H=8, Dh=64, TB=2048 rows.

typedef __bf16 bf16;
typedef __attribute__((ext_vector_type(8))) __bf16 bf16x8;
typedef __attribute__((ext_vector_type(4))) __bf16 bf16x4;
typedef __attribute__((ext_vector_type(4))) float f32x4;

__device__ __forceinline__ void gl_lds16(const bf16* g, bf16* l) {
  __builtin_amdgcn_global_load_lds((const __attribute__((address_space(1))) void*)g,
                                   (__attribute__((address_space(3))) void*)l, 16, 0, 0);
}

// ---------------------------------------------------------------- prep ----
// Fragment-linear layout for a (K,N) operand B[k][n]:
//   elem d: frag=d>>9, lane=(d>>3)&63, j=d&7; kt=frag/NT, nt=frag%NT;
//   k = kt*32 + (lane>>4)*8 + j, n = nt*16 + (lane&15).
//   => offset within frag for (kl=k&31, nl=n&15): (kl>>3)*128 + nl*8 + (kl&7)

template <int NSRC, int NT>
__device__ __forceinline__ void convkn(int t, const float* __restrict__ W,
                                       bf16* __restrict__ dst) {
  int frag = t >> 5, r = t & 31;
  int lh = r >> 3, j = r & 7;   // kl = lh*8 + j
  int kt = frag / NT, nt = frag - kt * NT;
  int k = kt * 32 + lh * 8 + j;
  const float* src = W + (long)k * NSRC + nt * 16;
  f32x4 v0 = ((const f32x4*)src)[0], v1 = ((const f32x4*)src)[1];
  f32x4 v2 = ((const f32x4*)src)[2], v3 = ((const f32x4*)src)[3];
  bf16* d = dst + frag * 512 + lh * 128 + j;
  d[0] = (bf16)v0[0];  d[8] = (bf16)v0[1];  d[16] = (bf16)v0[2];  d[24] = (bf16)v0[3];
  d[32] = (bf16)v1[0]; d[40] = (bf16)v1[1]; d[48] = (bf16)v1[2];  d[56] = (bf16)v1[3];
  d[64] = (bf16)v2[0]; d[72] = (bf16)v2[1]; d[80] = (bf16)v2[2];  d[88] = (bf16)v2[3];
  d[96] = (bf16)v3[0]; d[104] = (bf16)v3[1]; d[112] = (bf16)v3[2]; d[120] = (bf16)v3[3];
}

__global__ void prep_kernel(const float* __restrict__ x,
                            const float* __restrict__ in_w,
                            const float* __restrict__ rel_w,
                            const float* __restrict__ out_w,
                            const float* __restrict__ fc1_w,
                            const float* __restrict__ fc2_w,
                            bf16* __restrict__ x_b,
                            bf16* __restrict__ inw_fl,
                            bf16* __restrict__ relw_fl,
                            bf16* __restrict__ outw_fl,
                            bf16* __restrict__ fc1w_fl,
                            bf16* __restrict__ fc2w_fl) {
  int t = blockIdx.x * 256 + threadIdx.x;
  if (t < 131072) {  // x -> bf16, 8/thread
    int d0 = t * 8;
    f32x4 a = *(const f32x4*)(x + d0), b = *(const f32x4*)(x + d0 + 4);
    bf16x8 r;
    r[0] = (bf16)a[0]; r[1] = (bf16)a[1]; r[2] = (bf16)a[2]; r[3] = (bf16)a[3];
    r[4] = (bf16)b[0]; r[5] = (bf16)b[1]; r[6] = (bf16)b[2]; r[7] = (bf16)b[3];
    *(bf16x8*)(x_b + d0) = r;
    return;
  }
  t -= 131072;
  if (t < 98304) {  // in_w (n,k) row-major: B[k][n]=in_w[n*512+k]; k-contig reads
    int d0 = t * 8;
    int frag = d0 >> 9, l = t & 63;
    int kt = frag / 96, nt = frag - kt * 96;
    const float* src = in_w + (long)(nt * 16 + (l & 15)) * 512 + kt * 32 + ((l >> 4) << 3);
    f32x4 a = *(const f32x4*)src, b = *(const f32x4*)(src + 4);
    bf16x8 r;
    r[0] = (bf16)a[0]; r[1] = (bf16)a[1]; r[2] = (bf16)a[2]; r[3] = (bf16)a[3];
    r[4] = (bf16)b[0]; r[5] = (bf16)b[1]; r[6] = (bf16)b[2]; r[7] = (bf16)b[3];
    *(bf16x8*)(inw_fl + d0) = r;
    return;
  }
  t -= 98304;
  if (t < 32768) { convkn<1024, 64>(t, rel_w, relw_fl); return; }
  t -= 32768;
  if (t < 16384) { convkn<512, 32>(t, out_w, outw_fl); return; }
  t -= 16384;
  if (t < 65536) { convkn<2048, 128>(t, fc1_w, fc1w_fl); return; }
  t -= 65536;
  if (t < 65536) { convkn<512, 32>(t, fc2_w, fc2w_fl); }
}

// ---------------------------------------------------------------- gemm ----
template <int WM, int WN, int MT, int NT, bool RELU, bool WF32, bool WBF16>
__global__ __launch_bounds__(256, 2) void gemm_bf16(
    const bf16* __restrict__ A, const bf16* __restrict__ Bfl,
    const float* __restrict__ bias, float* __restrict__ Cf,
    bf16* __restrict__ Cb, int M, int N, int K) {
  constexpr int AFR = WM * MT;
  constexpr int BFR = WN * NT;
  constexpr int NA = AFR / 4, NB = BFR / 4;
  __shared__ __align__(16) bf16 lA[2][AFR * 512];
  __shared__ __align__(16) bf16 lB[2][BFR * 512];
  const int tid = threadIdx.x, l = tid & 63, wv = tid >> 6;
  const int wm = wv / WN, wn = wv % WN;
  const int m0 = blockIdx.x * (AFR * 16), n0 = blockIdx.y * (BFR * 16);
  const int NTfr = N >> 4, nb0 = n0 >> 4, KT = K >> 5;

  f32x4 acc[MT][NT];
#pragma unroll
  for (int i = 0; i < MT; i++)
#pragma unroll
    for (int j = 0; j < NT; j++) acc[i][j] = (f32x4)0.f;

  const bf16* pA[NA];
#pragma unroll
  for (int i = 0; i < NA; ++i) {
    int f = wv + i * 4;
    pA[i] = A + (long)(m0 + f * 16 + (l & 15)) * K + ((l >> 4) << 3);
  }
  const bf16* pB[NB];
#pragma unroll
  for (int i = 0; i < NB; ++i) {
    int f = wv + i * 4;
    pB[i] = Bfl + (long)(nb0 + f) * 512 + l * 8;
  }
#pragma unroll
  for (int i = 0; i < NA; ++i) gl_lds16(pA[i], &lA[0][(wv + i * 4) * 512]);
#pragma unroll
  for (int i = 0; i < NB; ++i) gl_lds16(pB[i], &lB[0][(wv + i * 4) * 512]);

  for (int kt = 0; kt < KT; ++kt) {
    const int buf = kt & 1;
    __syncthreads();
    if (kt + 1 < KT) {
#pragma unroll
      for (int i = 0; i < NA; ++i)
        gl_lds16(pA[i] + (kt + 1) * 32, &lA[buf ^ 1][(wv + i * 4) * 512]);
#pragma unroll
      for (int i = 0; i < NB; ++i)
        gl_lds16(pB[i] + (long)(kt + 1) * NTfr * 512, &lB[buf ^ 1][(wv + i * 4) * 512]);
    }
    bf16x8 af[MT], bfr[NT];
#pragma unroll
    for (int mt = 0; mt < MT; ++mt)
      af[mt] = *(const bf16x8*)(&lA[buf][(wm * MT + mt) * 512 + l * 8]);
#pragma unroll
    for (int nt = 0; nt < NT; ++nt)
      bfr[nt] = *(const bf16x8*)(&lB[buf][(wn * NT + nt) * 512 + l * 8]);
#pragma unroll
    for (int mt = 0; mt < MT; ++mt)
#pragma unroll
      for (int nt = 0; nt < NT; ++nt)
        acc[mt][nt] = __builtin_amdgcn_mfma_f32_16x16x32_bf16(af[mt], bfr[nt],
                                                              acc[mt][nt], 0, 0, 0);
  }
#pragma unroll
  for (int nt = 0; nt < NT; nt++) {
    int n = n0 + (wn * NT + nt) * 16 + (l & 15);
    float bv = bias[n];
#pragma unroll
    for (int mt = 0; mt < MT; mt++) {
#pragma unroll
      for (int j = 0; j < 4; j++) {
        int row = m0 + (wm * MT + mt) * 16 + ((l >> 4) << 2) + j;
        float v = acc[mt][nt][j] + bv;
        if (RELU) v = fmaxf(v, 0.f);
        if (WF32) Cf[(long)row * N + n] = v;
        if (WBF16) Cb[(long)row * N + n] = (bf16)v;
      }
    }
  }
}

// ---------------------------------------------------------------- relw ----
// v4: block = 128 rows x 512 cols (4 heads: ra + rb), 1024 thr / 16 waves,
// wave tile 64x64 -> acc[4][4] (64 regs) -> ~4 waves/SIMD.
// B staged via global_load_lds (frag-linear straight copy, 32KB/step, shared).
// A (rel fp32) reg-staged + cvt, coalesced 16B loads, double-buffered LDS.
// ra/rb pairing via post-K-loop LDS accumulator exchange (128KB union).
// Wave w: mh=w>>3 (row half), nq=w&7: nq<4 -> ra head c*4+nq; else rb head.
__global__ __launch_bounds__(1024, 4) void relw_kernel(
    const float* __restrict__ rel, const bf16* __restrict__ relw_fl,
    const float* __restrict__ rel_bias, const float* __restrict__ qkv,
    float* __restrict__ wT) {
  __shared__ __align__(16) union U {
    struct { bf16 A[2][8 * 512]; bf16 B[2][32 * 512]; } s;  // 16KB + 64KB
    float post[16][2048];                                   // 128KB
  } u;
  const int tid = threadIdx.x, l = tid & 63, w = tid >> 6;
  const int mh = w >> 3, nq = w & 7;
  const int tile = blockIdx.x >> 1, c = blockIdx.x & 1;
  const int t1 = tile >> 4;
  const int fb0 = (nq < 4) ? nq * 4 : 16 + (nq - 4) * 4;

  f32x4 acc[4][4];
#pragma unroll
  for (int i = 0; i < 4; i++)
#pragma unroll
    for (int j = 0; j < 4; j++) acc[i][j] = (f32x4)0.f;

  // A staging map: e = 4*tid elems of the 128x32 tile image
  const int sfm = tid >> 7;                 // frag 0..7
  const int slane = (tid >> 1) & 63;        // frag-lane
  const int sj = (tid & 1) * 4;             // j 0 or 4
  const int srow = tile * 128 + sfm * 16 + (slane & 15);
  const int skof = ((slane >> 4) << 3) + sj;  // k within BK
  const float* asrc = rel + (long)srow * 512 + skof;
  const int adst = sfm * 512 + slane * 8 + sj;  // elem offset in lA image

  // B gl_lds sources: wave w covers local frags {w} and {16+w}
  const bf16* bsrc1 = relw_fl + ((long)(c * 16 + w)) * 512 + l * 8;
  const bf16* bsrc2 = relw_fl + ((long)(32 + c * 16 + w)) * 512 + l * 8;

  // prologue: stage kt=0
  {
    f32x4 a0 = *(const f32x4*)asrc;
    bf16x4 cv;
    cv[0] = (bf16)a0[0]; cv[1] = (bf16)a0[1]; cv[2] = (bf16)a0[2]; cv[3] = (bf16)a0[3];
    *(bf16x4*)(&u.s.A[0][adst]) = cv;
    gl_lds16(bsrc1, &u.s.B[0][w * 512]);
    gl_lds16(bsrc2, &u.s.B[0][(16 + w) * 512]);
  }
  f32x4 stg = *(const f32x4*)(asrc + 32);  // A(kt=1)

  for (int kt = 0; kt < 16; ++kt) {
    const int buf = kt & 1;
    __syncthreads();  // stage(kt) complete (vmcnt+lgkm), prev reads drained
    if (kt + 1 < 16) {
      gl_lds16(bsrc1 + (long)(kt + 1) * 32768, &u.s.B[buf ^ 1][w * 512]);
      gl_lds16(bsrc2 + (long)(kt + 1) * 32768, &u.s.B[buf ^ 1][(16 + w) * 512]);
      bf16x4 cv;
      cv[0] = (bf16)stg[0]; cv[1] = (bf16)stg[1]; cv[2] = (bf16)stg[2]; cv[3] = (bf16)stg[3];
      *(bf16x4*)(&u.s.A[buf ^ 1][adst]) = cv;
      if (kt + 2 < 16) stg = *(const f32x4*)(asrc + (kt + 2) * 32);
    }
    bf16x8 af[4];
#pragma unroll
    for (int mt = 0; mt < 4; ++mt)
      af[mt] = *(const bf16x8*)(&u.s.A[buf][(mh * 4 + mt) * 512 + l * 8]);
#pragma unroll
    for (int nt = 0; nt < 4; ++nt) {
      bf16x8 bf = *(const bf16x8*)(&u.s.B[buf][(fb0 + nt) * 512 + l * 8]);
#pragma unroll
      for (int mt = 0; mt < 4; ++mt)
        acc[mt][nt] = __builtin_amdgcn_mfma_f32_16x16x32_bf16(af[mt], bf,
                                                              acc[mt][nt], 0, 0, 0);
    }
  }

  // ---- pairing exchange: every wave stashes its partner-half accumulators
  __syncthreads();
  {
    float* dst = &u.post[w][0];
#pragma unroll
    for (int mt2 = 0; mt2 < 2; ++mt2) {
      int mt = (nq < 4) ? (2 + mt2) : mt2;  // ra stash mt 2,3 ; rb stash mt 0,1
#pragma unroll
      for (int nt = 0; nt < 4; ++nt)
        *(f32x4*)&dst[(mt2 * 4 + nt) * 256 + l * 4] = acc[mt][nt];
    }
  }
  __syncthreads();

  // ---- epilogue: w[i=t2,j=t1,bh] = (1/64) * sum_dh (q+ra+ba)(k+rb+bb)
  const int hq = nq & 3, h = c * 4 + hq, dhb = h * 64;
  const int wp = (nq < 4) ? (w + 4) : (w - 4);
  const int mtbase = (nq < 4) ? 0 : 2;
  const int tt = tile & 15;
#pragma unroll
  for (int mt2 = 0; mt2 < 2; ++mt2) {
    int mt = mtbase + mt2;
    float psum[4] = {0.f, 0.f, 0.f, 0.f};
#pragma unroll
    for (int nt = 0; nt < 4; ++nt) {
      int dh = nt * 16 + (l & 15);
      float ba = rel_bias[dhb + dh];
      float bb = rel_bias[512 + dhb + dh];
      f32x4 part = *(const f32x4*)&u.post[wp][(mt2 * 4 + nt) * 256 + l * 4];
      f32x4 rav, rbv;
      if (nq < 4) { rav = acc[mt][nt]; rbv = part; }
      else        { rav = part;        rbv = acc[mt][nt]; }
#pragma unroll
      for (int j = 0; j < 4; ++j) {
        int rl = mh * 64 + mt * 16 + ((l >> 4) << 2) + j;
        int t2b = tt * 128 + rl;  // = t2*32 + b
        float qv = qkv[(long)t2b * 1536 + dhb + dh];
        float kv = qkv[(long)(t1 * 32 + (rl & 31)) * 1536 + 512 + dhb + dh];
        psum[j] += (qv + rav[j] + ba) * (kv + rbv[j] + bb);
      }
    }
#pragma unroll
    for (int j = 0; j < 4; ++j) {
      float v = psum[j];
      v += __shfl_xor(v, 1);
      v += __shfl_xor(v, 2);
      v += __shfl_xor(v, 4);
      v += __shfl_xor(v, 8);
      if ((l & 15) == 0) {
        int rl = mh * 64 + mt * 16 + ((l >> 4) << 2) + j;
        int t2b = tt * 128 + rl;
        wT[((long)t2b * 8 + h) * 64 + t1] = v * 0.015625f;
      }
    }
  }
}

// ---------------------------------------------------------------- attn ----
__global__ __launch_bounds__(256) void attn_kernel(const float* __restrict__ wT,
                                                   const float* __restrict__ qkv,
                                                   bf16* __restrict__ attn_b) {
  __shared__ __align__(16) float s[64][68];
  __shared__ __align__(16) float vl[64][68];
  __shared__ float pm[64][4], ps[64][4];
  const int tid = threadIdx.x;
  const int b = blockIdx.x >> 3, h = blockIdx.x & 7;
  const int i = tid >> 2, g = tid & 3;

  const float* wsrc = wT + ((long)i * 256 + b * 8 + h) * 64 + g * 16;
  f32x4 w0 = ((const f32x4*)wsrc)[0], w1 = ((const f32x4*)wsrc)[1];
  f32x4 w2 = ((const f32x4*)wsrc)[2], w3 = ((const f32x4*)wsrc)[3];
  const float* vsrc = qkv + ((long)i * 32 + b) * 1536 + 1024 + h * 64 + g * 16;
  f32x4 v0 = ((const f32x4*)vsrc)[0], v1 = ((const f32x4*)vsrc)[1];
  f32x4 v2 = ((const f32x4*)vsrc)[2], v3 = ((const f32x4*)vsrc)[3];
  *(f32x4*)&vl[i][g * 16] = v0;
  *(f32x4*)&vl[i][g * 16 + 4] = v1;
  *(f32x4*)&vl[i][g * 16 + 8] = v2;
  *(f32x4*)&vl[i][g * 16 + 12] = v3;
  float pmax = -1e30f;
#pragma unroll
  for (int uu = 0; uu < 4; ++uu) {
    pmax = fmaxf(pmax, fmaxf(fmaxf(w0[uu], w1[uu]), fmaxf(w2[uu], w3[uu])));
  }
  pm[i][g] = pmax;
  __syncthreads();
  float m = fmaxf(fmaxf(pm[i][0], pm[i][1]), fmaxf(pm[i][2], pm[i][3]));
  float psum = 0.f;
  f32x4 e0, e1, e2, e3;
#pragma unroll
  for (int uu = 0; uu < 4; ++uu) {
    e0[uu] = __expf(w0[uu] - m); psum += e0[uu];
    e1[uu] = __expf(w1[uu] - m); psum += e1[uu];
    e2[uu] = __expf(w2[uu] - m); psum += e2[uu];
    e3[uu] = __expf(w3[uu] - m); psum += e3[uu];
  }
  *(f32x4*)&s[i][g * 16] = e0;
  *(f32x4*)&s[i][g * 16 + 4] = e1;
  *(f32x4*)&s[i][g * 16 + 8] = e2;
  *(f32x4*)&s[i][g * 16 + 12] = e3;
  ps[i][g] = psum;
  __syncthreads();
  float scale = 1.f / (ps[i][0] + ps[i][1] + ps[i][2] + ps[i][3]);
  f32x4 o0 = (f32x4)0.f, o1 = (f32x4)0.f, o2 = (f32x4)0.f, o3 = (f32x4)0.f;
  for (int j = 0; j < 64; ++j) {
    float pj = s[i][j];
    const float* vr = &vl[j][g * 16];
    f32x4 a0 = ((const f32x4*)vr)[0], a1 = ((const f32x4*)vr)[1];
    f32x4 a2 = ((const f32x4*)vr)[2], a3 = ((const f32x4*)vr)[3];
#pragma unroll
    for (int uu = 0; uu < 4; ++uu) {
      o0[uu] = fmaf(pj, a0[uu], o0[uu]);
      o1[uu] = fmaf(pj, a1[uu], o1[uu]);
      o2[uu] = fmaf(pj, a2[uu], o2[uu]);
      o3[uu] = fmaf(pj, a3[uu], o3[uu]);
    }
  }
  bf16x8 r0, r1;
#pragma unroll
  for (int uu = 0; uu < 4; ++uu) {
    r0[uu] = (bf16)(o0[uu] * scale);
    r0[4 + uu] = (bf16)(o1[uu] * scale);
    r1[uu] = (bf16)(o2[uu] * scale);
    r1[4 + uu] = (bf16)(o3[uu] * scale);
  }
  bf16* dst = attn_b + ((long)i * 32 + b) * 512 + h * 64 + g * 16;
  *(bf16x8*)dst = r0;
  *(bf16x8*)(dst + 8) = r1;
}

// ------------------------------------------------------------------ ln ----
template <bool WB>
__global__ __launch_bounds__(256) void ln_kernel(const float* __restrict__ a,
                                                 const float* __restrict__ res,
                                                 const float* __restrict__ g,
                                                 const float* __restrict__ bb,
                                                 float* __restrict__ of,
                                                 bf16* __restrict__ ob) {
  const int l = threadIdx.x & 63;
  const int row = blockIdx.x * 4 + (threadIdx.x >> 6);
  const float* pa = a + (long)row * 512;
  const float* pr = res + (long)row * 512;
  float xv[8];
  float s = 0.f, sq = 0.f;
#pragma unroll
  for (int uu = 0; uu < 8; ++uu) {
    xv[uu] = pa[uu * 64 + l] + pr[uu * 64 + l];
    s += xv[uu];
    sq += xv[uu] * xv[uu];
  }
#pragma unroll
  for (int st = 1; st < 64; st <<= 1) {
    s += __shfl_xor(s, st);
    sq += __shfl_xor(sq, st);
  }
  float mean = s * (1.f / 512.f);
  float var = sq * (1.f / 512.f) - mean * mean;
  float rstd = rsqrtf(var + 1e-5f);
#pragma unroll
  for (int uu = 0; uu < 8; ++uu) {
    int e = uu * 64 + l;
    float v = (xv[uu] - mean) * rstd * g[e] + bb[e];
    of[(long)row * 512 + e] = v;
    if (WB) ob[(long)row * 512 + e] = (bf16)v;
  }
}

// -------------------------------------------------------------- launch ----
extern "C" void kernel_launch(void* const* d_in, const int* in_sizes, int n_in,
                              void* d_out, int out_size, void* d_ws, size_t ws_size,
                              hipStream_t stream) {
  const float* x     = (const float*)d_in[0];
  const float* rel   = (const float*)d_in[1];
  const float* in_w  = (const float*)d_in[2];
  const float* in_b  = (const float*)d_in[3];
  const float* rel_w = (const float*)d_in[4];
  const float* rel_b = (const float*)d_in[5];
  const float* out_w = (const float*)d_in[6];
  const float* out_b = (const float*)d_in[7];
  const float* fc1_w = (const float*)d_in[8];
  const float* fc1_b = (const float*)d_in[9];
  const float* fc2_w = (const float*)d_in[10];
  const float* fc2_b = (const float*)d_in[11];
  const float* ln1_g = (const float*)d_in[12];
  const float* ln1_b = (const float*)d_in[13];
  const float* ln2_g = (const float*)d_in[14];
  const float* ln2_b = (const float*)d_in[15];

  char* ws = (char*)d_ws;
  float* qkv   = (float*)(ws + 0);          // 12,582,912 B
  bf16* x_b    = (bf16*)(ws + 12582912);    //  2,097,152
  bf16* inw    = (bf16*)(ws + 14680064);    //  1,572,864
  bf16* relwB  = (bf16*)(ws + 16252928);    //  1,048,576
  bf16* outwB  = (bf16*)(ws + 17301504);    //    524,288
  bf16* fc1wB  = (bf16*)(ws + 17825792);    //  2,097,152
  bf16* fc2wB  = (bf16*)(ws + 19922944);    //  2,097,152
  float* wT    = (float*)(ws + 22020096);   //  4,194,304
  bf16* attn   = (bf16*)(ws + 26214400);    //  2,097,152
  float* opre  = (float*)(ws + 28311552);   //  4,194,304
  float* hf    = (float*)(ws + 32505856);   //  4,194,304
  bf16* hb     = (bf16*)(ws + 36700160);    //  2,097,152
  bf16* fb     = (bf16*)(ws + 38797312);    //  8,388,608
  float* f2o   = (float*)(ws + 47185920);   //  4,194,304

  prep_kernel<<<1600, 256, 0, stream>>>(x, in_w, rel_w, out_w, fc1_w, fc2_w,
                                        x_b, inw, relwB, outwB, fc1wB, fc2wB);
  gemm_bf16<2, 2, 2, 4, false, true, false><<<dim3(32, 12), 256, 0, stream>>>(
      x_b, inw, in_b, qkv, nullptr, 2048, 1536, 512);
  relw_kernel<<<2048, 1024, 0, stream>>>(rel, relwB, rel_b, qkv, wT);
  attn_kernel<<<256, 256, 0, stream>>>(wT, qkv, attn);
  gemm_bf16<2, 2, 2, 2, false, true, false><<<dim3(32, 8), 256, 0, stream>>>(
      attn, outwB, out_b, opre, nullptr, 2048, 512, 512);
  ln_kernel<true><<<512, 256, 0, stream>>>(opre, x, ln1_g, ln1_b, hf, hb);
  gemm_bf16<2, 2, 4, 4, true, false, true><<<dim3(16, 16), 256, 0, stream>>>(
      hb, fc1wB, fc1_b, nullptr, fb, 2048, 2048, 512);
  gemm_bf16<2, 2, 2, 2, false, true, false><<<dim3(32, 8), 256, 0, stream>>>(
      fb, fc2wB, fc2_b, f2o, nullptr, 2048, 512, 2048);
  ln_kernel<false><<<512, 256, 0, stream>>>(f2o, hf, ln2_g, ln2_b, (float*)d_out,
                                            nullptr);
}